// Round 16
// baseline (332.496 us; speedup 1.0000x reference)
//
#include <hip/hip_runtime.h>
#include <hip/hip_bf16.h>
#include <math.h>

#define N_NODES 512
#define N_EDGES 4096
#define D_NODE 256
#define D3 768
#define H_GNN 512
#define N_OBJ_CLS 160
#define N_REL_CLS 26

typedef __attribute__((ext_vector_type(8))) short bf16x8;   // 8 bf16 in 4 VGPRs
typedef __attribute__((ext_vector_type(4))) float f32x4;    // MFMA accumulator

__device__ __forceinline__ unsigned short f2bf(float x) {   // RNE f32 -> bf16 bits
  unsigned u = __float_as_uint(x);
  u = u + 0x7FFFu + ((u >> 16) & 1u);
  return (unsigned short)(u >> 16);
}
__device__ __forceinline__ float bf2f(unsigned short h) {
  return __uint_as_float(((unsigned)h) << 16);
}
// packed RNE cvt: a -> low16, b -> high16 (v_cvt_pk_bf16_f32)
__device__ __forceinline__ unsigned cvtpk(float a, float b) {
  __hip_bfloat162 h = __float22bfloat162_rn(make_float2(a, b));
  return *reinterpret_cast<unsigned*>(&h);
}
// T2 bank swizzle: XOR 16B-block index (short-bits 3-5) with (row>>1)&7.
// Pure bijection within each row's data region; keeps 4/8/16B alignment.
__device__ __forceinline__ int swz(int row, int colShort) {
  return colShort ^ (((row >> 1) & 7) << 3);
}

// ---------------- batched weight transpose+split: wt[n*K+k] = hi/lo(w[k*N+n]) ----
struct WEnt { const float* src; unsigned short* dh; unsigned short* dl; int K; int N; int start; };
struct WBatch { WEnt e[18]; int total; };

__global__ __launch_bounds__(256) void wtrans_batch(WBatch wb) {
  int idx = blockIdx.x * 256 + threadIdx.x;
  const int stride = gridDim.x * 256;
  for (; idx < wb.total; idx += stride) {
    int i = 0;
#pragma unroll
    for (int t = 1; t < 18; ++t) if (idx >= wb.e[t].start) i = t;
    const int local = idx - wb.e[i].start;
    const int K = wb.e[i].K;
    const int n = local / K, k = local - n * K;
    const float v = wb.e[i].src[k * wb.e[i].N + n];
    const unsigned short hi = f2bf(v);
    wb.e[i].dh[local] = hi;
    wb.e[i].dl[local] = f2bf(v - bf2f(hi));
  }
}

// ---------------- MFMA PointNet: 128-pt tiles, 8 waves, swizzled LDS --------------
template<int CIN, int PTOT, int NSPLIT>
__global__ __launch_bounds__(512) void pointnet_mfma(
    const float* __restrict__ in,
    const float* __restrict__ w1, const float* __restrict__ b1,
    const unsigned short* __restrict__ w2t, const float* __restrict__ b2,
    const unsigned short* __restrict__ w3t, const float* __restrict__ b3,
    unsigned short* __restrict__ outh,
    float* __restrict__ pmax)
{
  constexpr int PBLK = PTOT / NSPLIT;
  __shared__ unsigned short h1h[128 * 72];    // [pt][ch] 128x64, swizzled
  __shared__ unsigned short h2h[128 * 136];   // [pt][ch] 128x128, swizzled
  const int tid = threadIdx.x;
  const int wv = tid >> 6, l = tid & 63, lr = l & 15, lg = l >> 4;
  const int blk = blockIdx.x;
  const int b  = blk / NSPLIT;
  const int sp = blk % NSPLIT;
  const float* inb = in + (size_t)b * CIN * PTOT + (size_t)sp * PBLK;

  const int chA = 2 * (l & 31);
  const int sub = l >> 5;
  // read-side swizzle for frag rows (row = ntt*16+lr -> (row>>1)&7 == (lr>>1)&7)
  const int rsw = ((lr >> 1) & 7) << 3;
  float w1c0[CIN], w1c1[CIN];
#pragma unroll
  for (int c = 0; c < CIN; ++c) {
    w1c0[c] = w1[c * 64 + chA];
    w1c1[c] = w1[c * 64 + chA + 1];
  }
  const float b1v0 = b1[chA], b1v1 = b1[chA + 1];

  bf16x8 w2f[2];
#pragma unroll
  for (int kt = 0; kt < 2; ++kt)
    w2f[kt] = *(const bf16x8*)(w2t + (size_t)(16 * wv + lr) * 64 + kt * 32 + lg * 8);
  bf16x8 w3f[2][4];
#pragma unroll
  for (int mt = 0; mt < 2; ++mt)
#pragma unroll
    for (int kt = 0; kt < 4; ++kt)
      w3f[mt][kt] = *(const bf16x8*)(w3t + (size_t)(32 * wv + mt * 16 + lr) * 128 + kt * 32 + lg * 8);

  const float4 b2v = *(const float4*)&b2[16 * wv + lg * 4];

  f32x4 mxf[2];
#pragma unroll
  for (int mt = 0; mt < 2; ++mt) { f32x4 z = {-INFINITY, -INFINITY, -INFINITY, -INFINITY}; mxf[mt] = z; }

  for (int t0 = 0; t0 < PBLK; t0 += 128) {
    // ---- A: L1 f32; float4 loads (2 ch x 8 pts per lane); swizzled b32 writes ----
    {
      const int pl0 = wv * 16 + sub * 8;
      float4 xv0[CIN], xv1[CIN];
#pragma unroll
      for (int c = 0; c < CIN; ++c) {
        xv0[c] = *(const float4*)&inb[c * PTOT + t0 + pl0];
        xv1[c] = *(const float4*)&inb[c * PTOT + t0 + pl0 + 4];
      }
#pragma unroll
      for (int pp = 0; pp < 8; ++pp) {
        float a0 = b1v0, a1 = b1v1;
#pragma unroll
        for (int c = 0; c < CIN; ++c) {
          const float xc = (pp < 4) ? ((const float*)&xv0[c])[pp]
                                    : ((const float*)&xv1[c])[pp - 4];
          a0 = fmaf(xc, w1c0[c], a0);
          a1 = fmaf(xc, w1c1[c], a1);
        }
        a0 = fmaxf(a0, 0.f); a1 = fmaxf(a1, 0.f);
        const int row = pl0 + pp;
        *(unsigned*)&h1h[row * 72 + swz(row, chA)] = cvtpk(a0, a1);
      }
    }
    __syncthreads();
    // ---- B: L2; wave owns ch [16wv,+16), all 128 pts ----
#pragma unroll
    for (int ntt = 0; ntt < 8; ++ntt) {
      const int row = ntt * 16 + lr;
      bf16x8 bh[2];
#pragma unroll
      for (int kt = 0; kt < 2; ++kt)
        bh[kt] = *(const bf16x8*)&h1h[row * 72 + ((kt * 32 + lg * 8) ^ rsw)];
      f32x4 a = {0.f, 0.f, 0.f, 0.f};
#pragma unroll
      for (int kt = 0; kt < 2; ++kt)
        a = __builtin_amdgcn_mfma_f32_16x16x32_bf16(w2f[kt], bh[kt], a, 0, 0, 0);
      const float v0 = fmaxf(a[0] + b2v.x, 0.f);
      const float v1 = fmaxf(a[1] + b2v.y, 0.f);
      const float v2 = fmaxf(a[2] + b2v.z, 0.f);
      const float v3 = fmaxf(a[3] + b2v.w, 0.f);
      const int cc = 16 * wv + lg * 4;
      *(uint2*)&h2h[row * 136 + swz(row, cc)] = make_uint2(cvtpk(v0, v1), cvtpk(v2, v3));
    }
    __syncthreads();
    // ---- C: L3 + running max; wave owns ch [32wv,+32), all 128 pts ----
#pragma unroll
    for (int ntt = 0; ntt < 8; ++ntt) {
      const int row = ntt * 16 + lr;
      bf16x8 ah[4];
#pragma unroll
      for (int kt = 0; kt < 4; ++kt)
        ah[kt] = *(const bf16x8*)&h2h[row * 136 + ((kt * 32 + lg * 8) ^ rsw)];
#pragma unroll
      for (int mt = 0; mt < 2; ++mt) {
        f32x4 a = {0.f, 0.f, 0.f, 0.f};
#pragma unroll
        for (int kt = 0; kt < 4; ++kt)
          a = __builtin_amdgcn_mfma_f32_16x16x32_bf16(w3f[mt][kt], ah[kt], a, 0, 0, 0);
#pragma unroll
        for (int j = 0; j < 4; ++j) mxf[mt][j] = fmaxf(mxf[mt][j], a[j]);
      }
    }
    __syncthreads();
  }
  // reduce over the 16-lane point axis
#pragma unroll
  for (int mt = 0; mt < 2; ++mt)
#pragma unroll
    for (int j = 0; j < 4; ++j) {
      float v = mxf[mt][j];
      v = fmaxf(v, __shfl_xor(v, 1));
      v = fmaxf(v, __shfl_xor(v, 2));
      v = fmaxf(v, __shfl_xor(v, 4));
      v = fmaxf(v, __shfl_xor(v, 8));
      mxf[mt][j] = v;
    }
  if (lr == 0) {
    if (NSPLIT == 1) {
#pragma unroll
      for (int mt = 0; mt < 2; ++mt) {
        const int ch = 32 * wv + mt * 16 + lg * 4;
        const float4 b3v = *(const float4*)&b3[ch];
        const size_t o = (size_t)b * 256 + ch;
        *(uint2*)(outh + o) = make_uint2(cvtpk(mxf[mt][0] + b3v.x, mxf[mt][1] + b3v.y),
                                         cvtpk(mxf[mt][2] + b3v.z, mxf[mt][3] + b3v.w));
      }
    } else {
#pragma unroll
      for (int mt = 0; mt < 2; ++mt) {
        const int ch = 32 * wv + mt * 16 + lg * 4;
        const size_t o = ((size_t)b * NSPLIT + sp) * 256 + ch;
        *(float4*)&pmax[o] = make_float4(mxf[mt][0], mxf[mt][1], mxf[mt][2], mxf[mt][3]);
      }
    }
  }
}

template<int NSPLIT>
__global__ __launch_bounds__(256) void combine_max(
    const float* __restrict__ pmax, const float* __restrict__ b3,
    unsigned short* __restrict__ outh)
{
  const int b = blockIdx.x, ch = threadIdx.x;
  float m = pmax[(size_t)b * NSPLIT * 256 + ch];
#pragma unroll
  for (int s = 1; s < NSPLIT; ++s)
    m = fmaxf(m, pmax[((size_t)b * NSPLIT + s) * 256 + ch]);
  outh[(size_t)b * 256 + ch] = f2bf(m + b3[ch]);
}

// ---------------- MFMA GEMM body, BK=64 + T14 prefetch + swizzled LDS -------------
template<int ACT, int OUT, bool GATHER>
__device__ __forceinline__ void mgemm_body(
    const unsigned short* __restrict__ Ah, int lda,
    const unsigned short* __restrict__ Eh,
    const int* __restrict__ ei,
    const unsigned short* __restrict__ Wh, const unsigned short* __restrict__ Wl,
    const float* __restrict__ bias,
    unsigned short* __restrict__ Oh, int ldo,
    float* __restrict__ Of, float* __restrict__ pooled,
    int M, int N, int K, int bx, int by)
{
  __shared__ unsigned short sAh[64 * 72];
  __shared__ unsigned short sBh[64 * 72], sBl[64 * 72];
  __shared__ int sS[64], sO[64];
  const int tid = threadIdx.x;
  const int wv = tid >> 6, l = tid & 63, lr = l & 15, lg = l >> 4;
  const int wm = wv >> 1, wn = wv & 1;
  const int bm = by * 64, bn = bx * 64;
  const int srow = tid >> 3;        // 0..31
  const int sch  = (tid & 7) * 8;   // 0..56
  const int wsw = ((srow >> 1) & 7) << 3;   // write-side swizzle (rows it*32+srow)
  const int rsw = ((lr >> 1) & 7) << 3;     // read-side swizzle (rows *16+lr, *32 halves)

  if ((GATHER || OUT == 2) && tid < 64) {
    sS[tid] = ei[bm + tid];
    sO[tid] = ei[N_EDGES + bm + tid];
  }
  __syncthreads();

  float bv[2];
#pragma unroll
  for (int ni = 0; ni < 2; ++ni) {
    const int col = bn + wn * 32 + ni * 16 + lr;
    bv[ni] = (col < N) ? bias[col] : 0.f;
  }

  f32x4 acc[2][2];
#pragma unroll
  for (int mi = 0; mi < 2; ++mi)
#pragma unroll
    for (int ni = 0; ni < 2; ++ni) { f32x4 z = {0.f, 0.f, 0.f, 0.f}; acc[mi][ni] = z; }

  const int nsteps = K >> 6;

  auto loadA = [&](int k0, int it) -> bf16x8 {
    const int r = it * 32 + srow;
    const unsigned short* ph;
    if (GATHER) {
      const int kg = k0 + sch;
      if (kg < 256)      ph = Ah + (size_t)sS[r] * 256 + kg;
      else if (kg < 512) ph = Eh + (size_t)(bm + r) * 256 + (kg - 256);
      else               ph = Ah + (size_t)sO[r] * 256 + (kg - 512);
    } else {
      ph = Ah + (size_t)(bm + r) * lda + k0 + sch;
    }
    return *(const bf16x8*)ph;
  };
  auto loadB = [&](const unsigned short* W, int k0, int it) -> bf16x8 {
    int n = bn + it * 32 + srow;
    if (n >= N) n = N - 1;
    return *(const bf16x8*)(W + (size_t)n * K + k0 + sch);
  };

  bf16x8 rA[2], rBh[2], rBl[2];
#pragma unroll
  for (int it = 0; it < 2; ++it) {
    rA[it]  = loadA(0, it);
    rBh[it] = loadB(Wh, 0, it);
    rBl[it] = loadB(Wl, 0, it);
  }

  for (int t = 0; t < nsteps; ++t) {
    __syncthreads();
#pragma unroll
    for (int it = 0; it < 2; ++it) {
      const int r = it * 32 + srow;
      const int sc = sch ^ wsw;
      *(bf16x8*)&sAh[r * 72 + sc] = rA[it];
      *(bf16x8*)&sBh[r * 72 + sc] = rBh[it];
      *(bf16x8*)&sBl[r * 72 + sc] = rBl[it];
    }
    __syncthreads();
    if (t + 1 < nsteps) {
      const int k1 = (t + 1) << 6;
#pragma unroll
      for (int it = 0; it < 2; ++it) {
        rA[it]  = loadA(k1, it);
        rBh[it] = loadB(Wh, k1, it);
        rBl[it] = loadB(Wl, k1, it);
      }
    }
#pragma unroll
    for (int kt = 0; kt < 2; ++kt) {
      bf16x8 afh[2], bfh[2], bfl[2];
      const int cs = (kt * 32 + lg * 8) ^ rsw;
#pragma unroll
      for (int mi = 0; mi < 2; ++mi)
        afh[mi] = *(const bf16x8*)&sAh[(wm * 32 + mi * 16 + lr) * 72 + cs];
#pragma unroll
      for (int ni = 0; ni < 2; ++ni) {
        bfh[ni] = *(const bf16x8*)&sBh[(wn * 32 + ni * 16 + lr) * 72 + cs];
        bfl[ni] = *(const bf16x8*)&sBl[(wn * 32 + ni * 16 + lr) * 72 + cs];
      }
#pragma unroll
      for (int mi = 0; mi < 2; ++mi)
#pragma unroll
        for (int ni = 0; ni < 2; ++ni) {
          acc[mi][ni] = __builtin_amdgcn_mfma_f32_16x16x32_bf16(afh[mi], bfh[ni], acc[mi][ni], 0, 0, 0);
          acc[mi][ni] = __builtin_amdgcn_mfma_f32_16x16x32_bf16(afh[mi], bfl[ni], acc[mi][ni], 0, 0, 0);
        }
    }
  }
#pragma unroll
  for (int mi = 0; mi < 2; ++mi)
#pragma unroll
    for (int ni = 0; ni < 2; ++ni) {
      const int colb = bn + wn * 32 + ni * 16 + lr;
#pragma unroll
      for (int j = 0; j < 4; ++j) {
        const int lrow = wm * 32 + mi * 16 + lg * 4 + j;
        float v = acc[mi][ni][j] + bv[ni];
        if (ACT == 1) v = fmaxf(v, 0.f);
        else if (ACT == 2) v = 1.f / (1.f + expf(-v));
        if (OUT == 0) {
          if (colb < N) Oh[(size_t)(bm + lrow) * ldo + colb] = f2bf(v);
        } else if (OUT == 1) {
          if (colb < N) Of[(size_t)(bm + lrow) * ldo + colb] = v;
        } else {
          if (colb < 256) {
            atomicAdd(&pooled[(size_t)sS[lrow] * 256 + colb], v);
          } else if (colb < 512) {
            Oh[(size_t)(bm + lrow) * 256 + (colb - 256)] = f2bf(v);
          } else {
            atomicAdd(&pooled[(size_t)sO[lrow] * 256 + (colb - 512)], v);
          }
        }
      }
    }
}

template<int ACT, int OUT, bool GATHER>
__global__ __launch_bounds__(256) void mgemm(
    const unsigned short* __restrict__ Ah, int lda,
    const unsigned short* __restrict__ Eh,
    const int* __restrict__ ei,
    const unsigned short* __restrict__ Wh, const unsigned short* __restrict__ Wl,
    const float* __restrict__ bias,
    unsigned short* __restrict__ Oh, int ldo,
    float* __restrict__ Of, float* __restrict__ pooled,
    int M, int N, int K)
{
  mgemm_body<ACT, OUT, GATHER>(Ah, lda, Eh, ei, Wh, Wl, bias, Oh, ldo, Of, pooled,
                               M, N, K, blockIdx.x, blockIdx.y);
}

// ---------------- fused head layers (rel-chain || obj-chain) ----------------------
__global__ __launch_bounds__(256) void head12_fused(
    const unsigned short* __restrict__ rA, int rlda,
    const unsigned short* __restrict__ rWh, const unsigned short* __restrict__ rWl,
    const float* __restrict__ rbias, unsigned short* __restrict__ rO, int rldo,
    int rM, int rN, int rK, int rGX, int rGY,
    const unsigned short* __restrict__ oA, int olda,
    const unsigned short* __restrict__ oWh, const unsigned short* __restrict__ oWl,
    const float* __restrict__ obias, unsigned short* __restrict__ oO, int oldo,
    int oM, int oN, int oK, int oGX)
{
  int b = blockIdx.x;
  const int nrel = rGX * rGY;
  const bool isRel = b < nrel;
  if (!isRel) b -= nrel;
  mgemm_body<1, 0, false>(
      isRel ? rA : oA, isRel ? rlda : olda, nullptr, nullptr,
      isRel ? rWh : oWh, isRel ? rWl : oWl, isRel ? rbias : obias,
      isRel ? rO : oO, isRel ? rldo : oldo, nullptr, nullptr,
      isRel ? rM : oM, isRel ? rN : oN, isRel ? rK : oK,
      b % (isRel ? rGX : oGX), b / (isRel ? rGX : oGX));
}

__global__ __launch_bounds__(256) void head3_fused(
    const unsigned short* __restrict__ rA,
    const unsigned short* __restrict__ rWh, const unsigned short* __restrict__ rWl,
    const float* __restrict__ rbias, float* __restrict__ rOf,
    const unsigned short* __restrict__ oA,
    const unsigned short* __restrict__ oWh, const unsigned short* __restrict__ oWl,
    const float* __restrict__ obias, float* __restrict__ oOf)
{
  int b = blockIdx.x;
  if (b < 64)   // rel: grid (1,64), sigmoid, N=26
    mgemm_body<2, 1, false>(rA, 256, nullptr, nullptr, rWh, rWl, rbias,
                            nullptr, N_REL_CLS, rOf, nullptr, N_EDGES, N_REL_CLS, 256, 0, b);
  else {        // obj: grid (3,8), none, N=160
    b -= 64;
    mgemm_body<0, 1, false>(oA, 256, nullptr, nullptr, oWh, oWl, obias,
                            nullptr, N_OBJ_CLS, oOf, nullptr, N_NODES, N_OBJ_CLS, 256, b % 3, b / 3);
  }
}

// ---------------- helpers ----------------
__global__ __launch_bounds__(256) void count_kernel(const int* __restrict__ ei,
                                                    float* __restrict__ cnt)
{
  const int i = blockIdx.x * blockDim.x + threadIdx.x;
  if (i < 2 * N_EDGES) atomicAdd(&cnt[ei[i]], 1.0f);
}

__global__ __launch_bounds__(256) void avg_plane_kernel(const float* __restrict__ pooled,
                                                        const float* __restrict__ cnt,
                                                        unsigned short* __restrict__ ah)
{
  const int i = blockIdx.x * 256 + threadIdx.x;
  ah[i] = f2bf(pooled[i] / fmaxf(cnt[i >> 8], 1.0f));
}

__global__ __launch_bounds__(256) void logsoftmax_kernel(const float* __restrict__ logits,
                                                         float* __restrict__ out)
{
  __shared__ float red[256];
  const int r = blockIdx.x, tid = threadIdx.x;
  const float v = (tid < N_OBJ_CLS) ? logits[(size_t)r * N_OBJ_CLS + tid] : -INFINITY;
  red[tid] = v;
  __syncthreads();
  for (int s = 128; s > 0; s >>= 1) {
    if (tid < s) red[tid] = fmaxf(red[tid], red[tid + s]);
    __syncthreads();
  }
  const float mxv = red[0];
  __syncthreads();
  red[tid] = (tid < N_OBJ_CLS) ? expf(v - mxv) : 0.0f;
  __syncthreads();
  for (int s = 128; s > 0; s >>= 1) {
    if (tid < s) red[tid] += red[tid + s];
    __syncthreads();
  }
  const float lse = mxv + logf(red[0]);
  if (tid < N_OBJ_CLS) out[(size_t)r * N_OBJ_CLS + tid] = v - lse;
}

// ---------------- launch ----------------
extern "C" void kernel_launch(void* const* d_in, const int* in_sizes, int n_in,
                              void* d_out, int out_size, void* d_ws, size_t ws_size,
                              hipStream_t stream)
{
  const float* obj_points = (const float*)d_in[0];
  const float* rel_points = (const float*)d_in[1];
  const int*   edge_index = (const int*)d_in[2];
  const float* obj_w1 = (const float*)d_in[3];
  const float* obj_b1 = (const float*)d_in[4];
  const float* obj_w2 = (const float*)d_in[5];
  const float* obj_b2 = (const float*)d_in[6];
  const float* obj_w3 = (const float*)d_in[7];
  const float* obj_b3 = (const float*)d_in[8];
  const float* rel_w1 = (const float*)d_in[9];
  const float* rel_b1 = (const float*)d_in[10];
  const float* rel_w2 = (const float*)d_in[11];
  const float* rel_b2 = (const float*)d_in[12];
  const float* rel_w3 = (const float*)d_in[13];
  const float* rel_b3 = (const float*)d_in[14];
  const float* g_tw1 = (const float*)d_in[15];
  const float* g_tb1 = (const float*)d_in[16];
  const float* g_tw2 = (const float*)d_in[17];
  const float* g_tb2 = (const float*)d_in[18];
  const float* g_nw1 = (const float*)d_in[19];
  const float* g_nb1 = (const float*)d_in[20];
  const float* g_nw2 = (const float*)d_in[21];
  const float* g_nb2 = (const float*)d_in[22];
  const float* oc_w1 = (const float*)d_in[23];
  const float* oc_b1 = (const float*)d_in[24];
  const float* oc_w2 = (const float*)d_in[25];
  const float* oc_b2 = (const float*)d_in[26];
  const float* oc_w3 = (const float*)d_in[27];
  const float* oc_b3 = (const float*)d_in[28];
  const float* rc_w1 = (const float*)d_in[29];
  const float* rc_b1 = (const float*)d_in[30];
  const float* rc_w2 = (const float*)d_in[31];
  const float* rc_b2 = (const float*)d_in[32];
  const float* rc_w3 = (const float*)d_in[33];
  const float* rc_b3 = (const float*)d_in[34];
  float* out = (float*)d_out;

  // ---- workspace layout (activations hi-only; weights hi+lo) ----
  unsigned short* u = (unsigned short*)d_ws;
  size_t uo = 0;
  auto UA = [&](size_t n) { unsigned short* p = u + uo; uo += n; return p; };
  unsigned short* x0h = UA(131072);
  unsigned short* x1h = UA(131072);
  unsigned short* e0h = UA(1048576);
  unsigned short* neh = UA(1048576);
  unsigned short* h1h = UA(2097152);
  unsigned short* avgh = UA(131072);
  unsigned short* nhh = UA(262144);
  unsigned short* oh1 = UA(262144);   // obj head scratch 512x512
  unsigned short* oh2 = UA(131072);   // obj head scratch 512x256
  unsigned short* ow2h = UA(8192);   unsigned short* ow2l = UA(8192);
  unsigned short* ow3h = UA(32768);  unsigned short* ow3l = UA(32768);
  unsigned short* rw2h = UA(8192);   unsigned short* rw2l = UA(8192);
  unsigned short* rw3h = UA(32768);  unsigned short* rw3l = UA(32768);
  unsigned short* tw1h[2], *tw1l[2], *tw2h[2], *tw2l[2], *nw1h[2], *nw1l[2], *nw2h[2], *nw2l[2];
  for (int i = 0; i < 2; ++i) { tw1h[i] = UA(393216); tw1l[i] = UA(393216); }
  for (int i = 0; i < 2; ++i) { tw2h[i] = UA(393216); tw2l[i] = UA(393216); }
  for (int i = 0; i < 2; ++i) { nw1h[i] = UA(131072); nw1l[i] = UA(131072); }
  for (int i = 0; i < 2; ++i) { nw2h[i] = UA(131072); nw2l[i] = UA(131072); }
  unsigned short* oc1h = UA(131072); unsigned short* oc1l = UA(131072);
  unsigned short* oc2h = UA(131072); unsigned short* oc2l = UA(131072);
  unsigned short* oc3h = UA(40960);  unsigned short* oc3l = UA(40960);
  unsigned short* rc1h = UA(131072); unsigned short* rc1l = UA(131072);
  unsigned short* rc2h = UA(131072); unsigned short* rc2l = UA(131072);
  unsigned short* rc3h = UA(6656);   unsigned short* rc3l = UA(6656);
  float* f = (float*)(u + ((uo + 7) & ~(size_t)7));
  float* pooled = f;            // 512*256
  float* cntf   = f + 131072;   // 512
  float* logits = f + 131584;   // 512*160
  float* pmax   = f + 213504;   // 4*512*256 obj partial max
  unsigned short* hh1h = h1h;   // rel head scratch aliases dead GNN buffers
  unsigned short* hh2h = e0h;

  // ---- batched weight transpose/split ----
  WBatch wb;
  int cum = 0, wi = 0;
  auto ADD = [&](const float* src, unsigned short* dh, unsigned short* dl, int K, int N) {
    wb.e[wi].src = src; wb.e[wi].dh = dh; wb.e[wi].dl = dl;
    wb.e[wi].K = K; wb.e[wi].N = N; wb.e[wi].start = cum;
    cum += K * N; ++wi;
  };
  ADD(obj_w2, ow2h, ow2l, 64, 128);
  ADD(obj_w3, ow3h, ow3l, 128, 256);
  ADD(rel_w2, rw2h, rw2l, 64, 128);
  ADD(rel_w3, rw3h, rw3l, 128, 256);
  for (int i = 0; i < 2; ++i) ADD(g_tw1 + (size_t)i * 393216, tw1h[i], tw1l[i], 768, 512);
  for (int i = 0; i < 2; ++i) ADD(g_tw2 + (size_t)i * 393216, tw2h[i], tw2l[i], 512, 768);
  for (int i = 0; i < 2; ++i) ADD(g_nw1 + (size_t)i * 131072, nw1h[i], nw1l[i], 256, 512);
  for (int i = 0; i < 2; ++i) ADD(g_nw2 + (size_t)i * 131072, nw2h[i], nw2l[i], 512, 256);
  ADD(oc_w1, oc1h, oc1l, 256, 512);
  ADD(oc_w2, oc2h, oc2l, 512, 256);
  ADD(oc_w3, oc3h, oc3l, 256, 160);
  ADD(rc_w1, rc1h, rc1l, 256, 512);
  ADD(rc_w2, rc2h, rc2l, 512, 256);
  ADD(rc_w3, rc3h, rc3l, 256, 26);
  wb.total = cum;
  hipMemsetAsync(cntf, 0, 512 * sizeof(float), stream);
  wtrans_batch<<<4096, 256, 0, stream>>>(wb);

  // ---- PointNets (128-pt tiles, 8 waves, swizzled LDS) ----
  pointnet_mfma<3, 512, 4><<<N_NODES * 4, 512, 0, stream>>>(
      obj_points, obj_w1, obj_b1, ow2h, obj_b2, ow3h, obj_b3, nullptr, pmax);
  combine_max<4><<<N_NODES, 256, 0, stream>>>(pmax, obj_b3, x0h);
  pointnet_mfma<4, 256, 1><<<N_EDGES, 512, 0, stream>>>(
      rel_points, rel_w1, rel_b1, rw2h, rel_b2, rw3h, rel_b3, e0h, nullptr);

  // ---- degree counts ----
  count_kernel<<<32, 256, 0, stream>>>(edge_index, cntf);

  // ---- GNN layers ----
  unsigned short *xch = x0h, *xnh = x1h;
  unsigned short *ech = e0h;
  for (int ll = 0; ll < 2; ++ll) {
    mgemm<1, 0, true><<<dim3(8, 64), 256, 0, stream>>>(
        xch, 256, ech, edge_index, tw1h[ll], tw1l[ll], g_tb1 + ll * H_GNN,
        h1h, 512, nullptr, nullptr, N_EDGES, H_GNN, D3);
    hipMemsetAsync(pooled, 0, (size_t)N_NODES * D_NODE * sizeof(float), stream);
    mgemm<0, 2, false><<<dim3(12, 64), 256, 0, stream>>>(
        h1h, 512, nullptr, edge_index, tw2h[ll], tw2l[ll], g_tb2 + ll * D3,
        neh, 256, nullptr, pooled, N_EDGES, D3, H_GNN);
    avg_plane_kernel<<<512, 256, 0, stream>>>(pooled, cntf, avgh);
    mgemm<1, 0, false><<<dim3(8, 8), 256, 0, stream>>>(
        avgh, 256, nullptr, nullptr, nw1h[ll], nw1l[ll], g_nb1 + ll * H_GNN,
        nhh, 512, nullptr, nullptr, N_NODES, H_GNN, D_NODE);
    mgemm<0, 0, false><<<dim3(4, 8), 256, 0, stream>>>(
        nhh, 512, nullptr, nullptr, nw2h[ll], nw2l[ll], g_nb2 + ll * D_NODE,
        xnh, 256, nullptr, nullptr, N_NODES, D_NODE, H_GNN);
    unsigned short* t = xch; xch = xnh; xnh = t;
    ech = neh;
  }

  // ---- heads: rel-chain || obj-chain, fused per layer ----
  head12_fused<<<512 + 64, 256, 0, stream>>>(
      ech, 256, rc1h, rc1l, rc_b1, hh1h, 512, N_EDGES, 512, 256, 8, 64,
      xch, 256, oc1h, oc1l, oc_b1, oh1, 512, N_NODES, 512, 256, 8);
  head12_fused<<<256 + 32, 256, 0, stream>>>(
      hh1h, 512, rc2h, rc2l, rc_b2, hh2h, 256, N_EDGES, 256, 512, 4, 64,
      oh1, 512, oc2h, oc2l, oc_b2, oh2, 256, N_NODES, 256, 512, 4);
  head3_fused<<<64 + 24, 256, 0, stream>>>(
      hh2h, rc3h, rc3l, rc_b3, out + (size_t)N_NODES * N_OBJ_CLS,
      oh2, oc3h, oc3l, oc_b3, logits);
  logsoftmax_kernel<<<N_NODES, 256, 0, stream>>>(logits, out);
}

// Round 17
// 281.373 us; speedup vs baseline: 1.1817x; 1.1817x over previous
//
#include <hip/hip_runtime.h>
#include <hip/hip_bf16.h>
#include <math.h>

#define N_NODES 512
#define N_EDGES 4096
#define D_NODE 256
#define D3 768
#define H_GNN 512
#define N_OBJ_CLS 160
#define N_REL_CLS 26

typedef __attribute__((ext_vector_type(8))) short bf16x8;   // 8 bf16 in 4 VGPRs
typedef __attribute__((ext_vector_type(4))) float f32x4;    // MFMA accumulator

__device__ __forceinline__ unsigned short f2bf(float x) {   // RNE f32 -> bf16 bits
  unsigned u = __float_as_uint(x);
  u = u + 0x7FFFu + ((u >> 16) & 1u);
  return (unsigned short)(u >> 16);
}
__device__ __forceinline__ float bf2f(unsigned short h) {
  return __uint_as_float(((unsigned)h) << 16);
}
// packed RNE cvt: a -> low16, b -> high16 (v_cvt_pk_bf16_f32)
__device__ __forceinline__ unsigned cvtpk(float a, float b) {
  __hip_bfloat162 h = __float22bfloat162_rn(make_float2(a, b));
  return *reinterpret_cast<unsigned*>(&h);
}

// ---------------- batched weight transpose+split: wt[n*K+k] = hi/lo(w[k*N+n]) ----
struct WEnt { const float* src; unsigned short* dh; unsigned short* dl; int K; int N; int start; };
struct WBatch { WEnt e[18]; int total; };

__global__ __launch_bounds__(256) void wtrans_batch(WBatch wb) {
  int idx = blockIdx.x * 256 + threadIdx.x;
  const int stride = gridDim.x * 256;
  for (; idx < wb.total; idx += stride) {
    int i = 0;
#pragma unroll
    for (int t = 1; t < 18; ++t) if (idx >= wb.e[t].start) i = t;
    const int local = idx - wb.e[i].start;
    const int K = wb.e[i].K;
    const int n = local / K, k = local - n * K;
    const float v = wb.e[i].src[k * wb.e[i].N + n];
    const unsigned short hi = f2bf(v);
    wb.e[i].dh[local] = hi;
    wb.e[i].dl[local] = f2bf(v - bf2f(hi));
  }
}

// ---------------- MFMA PointNet: 128-pt tiles, 8 waves, hi-only activations -------
// Wave wv: A) points [16wv,16wv+16) x 64ch; B) ch [16wv,+16) x 128pts;
// C) ch [32wv,+32) x 128pts + running max.
template<int CIN, int PTOT, int NSPLIT>
__global__ __launch_bounds__(512) void pointnet_mfma(
    const float* __restrict__ in,
    const float* __restrict__ w1, const float* __restrict__ b1,
    const unsigned short* __restrict__ w2t, const float* __restrict__ b2,
    const unsigned short* __restrict__ w3t, const float* __restrict__ b3,
    unsigned short* __restrict__ outh,
    float* __restrict__ pmax)
{
  constexpr int PBLK = PTOT / NSPLIT;
  __shared__ unsigned short h1h[128][72];    // [pt][ch] 128x64
  __shared__ unsigned short h2h[128][136];   // [pt][ch] 128x128
  const int tid = threadIdx.x;
  const int wv = tid >> 6, l = tid & 63, lr = l & 15, lg = l >> 4;
  const int blk = blockIdx.x;
  const int b  = blk / NSPLIT;
  const int sp = blk % NSPLIT;
  const float* inb = in + (size_t)b * CIN * PTOT + (size_t)sp * PBLK;

  const int chA = 2 * (l & 31);
  const int sub = l >> 5;
  float w1c0[CIN], w1c1[CIN];
#pragma unroll
  for (int c = 0; c < CIN; ++c) {
    w1c0[c] = w1[c * 64 + chA];
    w1c1[c] = w1[c * 64 + chA + 1];
  }
  const float b1v0 = b1[chA], b1v1 = b1[chA + 1];

  // B: wave owns 16 ch -> 2 frags; C: wave owns 32 ch -> 8 frags
  bf16x8 w2f[2];
#pragma unroll
  for (int kt = 0; kt < 2; ++kt)
    w2f[kt] = *(const bf16x8*)(w2t + (size_t)(16 * wv + lr) * 64 + kt * 32 + lg * 8);
  bf16x8 w3f[2][4];
#pragma unroll
  for (int mt = 0; mt < 2; ++mt)
#pragma unroll
    for (int kt = 0; kt < 4; ++kt)
      w3f[mt][kt] = *(const bf16x8*)(w3t + (size_t)(32 * wv + mt * 16 + lr) * 128 + kt * 32 + lg * 8);

  const float4 b2v = *(const float4*)&b2[16 * wv + lg * 4];

  f32x4 mxf[2];
#pragma unroll
  for (int mt = 0; mt < 2; ++mt) { f32x4 z = {-INFINITY, -INFINITY, -INFINITY, -INFINITY}; mxf[mt] = z; }

  for (int t0 = 0; t0 < PBLK; t0 += 128) {
    // ---- A: L1 f32; vectorized float4 input loads (2 ch x 8 pts per lane) ----
    {
      const int pl0 = wv * 16 + sub * 8;
      float4 xv0[CIN], xv1[CIN];
#pragma unroll
      for (int c = 0; c < CIN; ++c) {
        xv0[c] = *(const float4*)&inb[c * PTOT + t0 + pl0];
        xv1[c] = *(const float4*)&inb[c * PTOT + t0 + pl0 + 4];
      }
#pragma unroll
      for (int pp = 0; pp < 8; ++pp) {
        float a0 = b1v0, a1 = b1v1;
#pragma unroll
        for (int c = 0; c < CIN; ++c) {
          const float xc = (pp < 4) ? ((const float*)&xv0[c])[pp]
                                    : ((const float*)&xv1[c])[pp - 4];
          a0 = fmaf(xc, w1c0[c], a0);
          a1 = fmaf(xc, w1c1[c], a1);
        }
        a0 = fmaxf(a0, 0.f); a1 = fmaxf(a1, 0.f);
        *(unsigned*)&h1h[pl0 + pp][chA] = cvtpk(a0, a1);
      }
    }
    __syncthreads();
    // ---- B: L2; wave owns ch [16wv,+16), all 128 pts ----
#pragma unroll
    for (int ntt = 0; ntt < 8; ++ntt) {
      bf16x8 bh[2];
#pragma unroll
      for (int kt = 0; kt < 2; ++kt)
        bh[kt] = *(const bf16x8*)&h1h[ntt * 16 + lr][kt * 32 + lg * 8];
      f32x4 a = {0.f, 0.f, 0.f, 0.f};
#pragma unroll
      for (int kt = 0; kt < 2; ++kt)
        a = __builtin_amdgcn_mfma_f32_16x16x32_bf16(w2f[kt], bh[kt], a, 0, 0, 0);
      const float v0 = fmaxf(a[0] + b2v.x, 0.f);
      const float v1 = fmaxf(a[1] + b2v.y, 0.f);
      const float v2 = fmaxf(a[2] + b2v.z, 0.f);
      const float v3 = fmaxf(a[3] + b2v.w, 0.f);
      const int pr = ntt * 16 + lr, cc = 16 * wv + lg * 4;
      *(uint2*)&h2h[pr][cc] = make_uint2(cvtpk(v0, v1), cvtpk(v2, v3));
    }
    __syncthreads();
    // ---- C: L3 + running max; wave owns ch [32wv,+32), all 128 pts ----
#pragma unroll
    for (int ntt = 0; ntt < 8; ++ntt) {
      bf16x8 ah[4];
#pragma unroll
      for (int kt = 0; kt < 4; ++kt)
        ah[kt] = *(const bf16x8*)&h2h[ntt * 16 + lr][kt * 32 + lg * 8];
#pragma unroll
      for (int mt = 0; mt < 2; ++mt) {
        f32x4 a = {0.f, 0.f, 0.f, 0.f};
#pragma unroll
        for (int kt = 0; kt < 4; ++kt)
          a = __builtin_amdgcn_mfma_f32_16x16x32_bf16(w3f[mt][kt], ah[kt], a, 0, 0, 0);
#pragma unroll
        for (int j = 0; j < 4; ++j) mxf[mt][j] = fmaxf(mxf[mt][j], a[j]);
      }
    }
    __syncthreads();
  }
  // reduce over the 16-lane point axis
#pragma unroll
  for (int mt = 0; mt < 2; ++mt)
#pragma unroll
    for (int j = 0; j < 4; ++j) {
      float v = mxf[mt][j];
      v = fmaxf(v, __shfl_xor(v, 1));
      v = fmaxf(v, __shfl_xor(v, 2));
      v = fmaxf(v, __shfl_xor(v, 4));
      v = fmaxf(v, __shfl_xor(v, 8));
      mxf[mt][j] = v;
    }
  if (lr == 0) {
    if (NSPLIT == 1) {
#pragma unroll
      for (int mt = 0; mt < 2; ++mt) {
        const int ch = 32 * wv + mt * 16 + lg * 4;
        const float4 b3v = *(const float4*)&b3[ch];
        const size_t o = (size_t)b * 256 + ch;
        *(uint2*)(outh + o) = make_uint2(cvtpk(mxf[mt][0] + b3v.x, mxf[mt][1] + b3v.y),
                                         cvtpk(mxf[mt][2] + b3v.z, mxf[mt][3] + b3v.w));
      }
    } else {
#pragma unroll
      for (int mt = 0; mt < 2; ++mt) {
        const int ch = 32 * wv + mt * 16 + lg * 4;
        const size_t o = ((size_t)b * NSPLIT + sp) * 256 + ch;
        *(float4*)&pmax[o] = make_float4(mxf[mt][0], mxf[mt][1], mxf[mt][2], mxf[mt][3]);
      }
    }
  }
}

template<int NSPLIT>
__global__ __launch_bounds__(256) void combine_max(
    const float* __restrict__ pmax, const float* __restrict__ b3,
    unsigned short* __restrict__ outh)
{
  const int b = blockIdx.x, ch = threadIdx.x;
  float m = pmax[(size_t)b * NSPLIT * 256 + ch];
#pragma unroll
  for (int s = 1; s < NSPLIT; ++s)
    m = fmaxf(m, pmax[((size_t)b * NSPLIT + s) * 256 + ch]);
  outh[(size_t)b * 256 + ch] = f2bf(m + b3[ch]);
}

// ---------------- MFMA GEMM body, BK=64 + T14 register prefetch (round-11) --------
template<int ACT, int OUT, bool GATHER>
__device__ __forceinline__ void mgemm_body(
    const unsigned short* __restrict__ Ah, int lda,
    const unsigned short* __restrict__ Eh,
    const int* __restrict__ ei,
    const unsigned short* __restrict__ Wh, const unsigned short* __restrict__ Wl,
    const float* __restrict__ bias,
    unsigned short* __restrict__ Oh, int ldo,
    float* __restrict__ Of, float* __restrict__ pooled,
    int M, int N, int K, int bx, int by)
{
  __shared__ unsigned short sAh[64][72];
  __shared__ unsigned short sBh[64][72], sBl[64][72];
  __shared__ int sS[64], sO[64];
  const int tid = threadIdx.x;
  const int wv = tid >> 6, l = tid & 63, lr = l & 15, lg = l >> 4;
  const int wm = wv >> 1, wn = wv & 1;
  const int bm = by * 64, bn = bx * 64;
  const int srow = tid >> 3;        // 0..31
  const int sch  = (tid & 7) * 8;   // 0..56

  if ((GATHER || OUT == 2) && tid < 64) {
    sS[tid] = ei[bm + tid];
    sO[tid] = ei[N_EDGES + bm + tid];
  }
  __syncthreads();

  float bv[2];
#pragma unroll
  for (int ni = 0; ni < 2; ++ni) {
    const int col = bn + wn * 32 + ni * 16 + lr;
    bv[ni] = (col < N) ? bias[col] : 0.f;
  }

  f32x4 acc[2][2];
#pragma unroll
  for (int mi = 0; mi < 2; ++mi)
#pragma unroll
    for (int ni = 0; ni < 2; ++ni) { f32x4 z = {0.f, 0.f, 0.f, 0.f}; acc[mi][ni] = z; }

  const int nsteps = K >> 6;

  auto loadA = [&](int k0, int it) -> bf16x8 {
    const int r = it * 32 + srow;
    const unsigned short* ph;
    if (GATHER) {
      const int kg = k0 + sch;
      if (kg < 256)      ph = Ah + (size_t)sS[r] * 256 + kg;
      else if (kg < 512) ph = Eh + (size_t)(bm + r) * 256 + (kg - 256);
      else               ph = Ah + (size_t)sO[r] * 256 + (kg - 512);
    } else {
      ph = Ah + (size_t)(bm + r) * lda + k0 + sch;
    }
    return *(const bf16x8*)ph;
  };
  auto loadB = [&](const unsigned short* W, int k0, int it) -> bf16x8 {
    int n = bn + it * 32 + srow;
    if (n >= N) n = N - 1;
    return *(const bf16x8*)(W + (size_t)n * K + k0 + sch);
  };

  bf16x8 rA[2], rBh[2], rBl[2];
#pragma unroll
  for (int it = 0; it < 2; ++it) {
    rA[it]  = loadA(0, it);
    rBh[it] = loadB(Wh, 0, it);
    rBl[it] = loadB(Wl, 0, it);
  }

  for (int t = 0; t < nsteps; ++t) {
    __syncthreads();
#pragma unroll
    for (int it = 0; it < 2; ++it) {
      *(bf16x8*)&sAh[it * 32 + srow][sch] = rA[it];
      *(bf16x8*)&sBh[it * 32 + srow][sch] = rBh[it];
      *(bf16x8*)&sBl[it * 32 + srow][sch] = rBl[it];
    }
    __syncthreads();
    if (t + 1 < nsteps) {
      const int k1 = (t + 1) << 6;
#pragma unroll
      for (int it = 0; it < 2; ++it) {
        rA[it]  = loadA(k1, it);
        rBh[it] = loadB(Wh, k1, it);
        rBl[it] = loadB(Wl, k1, it);
      }
    }
#pragma unroll
    for (int kt = 0; kt < 2; ++kt) {
      bf16x8 afh[2], bfh[2], bfl[2];
#pragma unroll
      for (int mi = 0; mi < 2; ++mi)
        afh[mi] = *(const bf16x8*)&sAh[wm * 32 + mi * 16 + lr][kt * 32 + lg * 8];
#pragma unroll
      for (int ni = 0; ni < 2; ++ni) {
        bfh[ni] = *(const bf16x8*)&sBh[wn * 32 + ni * 16 + lr][kt * 32 + lg * 8];
        bfl[ni] = *(const bf16x8*)&sBl[wn * 32 + ni * 16 + lr][kt * 32 + lg * 8];
      }
#pragma unroll
      for (int mi = 0; mi < 2; ++mi)
#pragma unroll
        for (int ni = 0; ni < 2; ++ni) {
          acc[mi][ni] = __builtin_amdgcn_mfma_f32_16x16x32_bf16(afh[mi], bfh[ni], acc[mi][ni], 0, 0, 0);
          acc[mi][ni] = __builtin_amdgcn_mfma_f32_16x16x32_bf16(afh[mi], bfl[ni], acc[mi][ni], 0, 0, 0);
        }
    }
  }
#pragma unroll
  for (int mi = 0; mi < 2; ++mi)
#pragma unroll
    for (int ni = 0; ni < 2; ++ni) {
      const int colb = bn + wn * 32 + ni * 16 + lr;
#pragma unroll
      for (int j = 0; j < 4; ++j) {
        const int lrow = wm * 32 + mi * 16 + lg * 4 + j;
        float v = acc[mi][ni][j] + bv[ni];
        if (ACT == 1) v = fmaxf(v, 0.f);
        else if (ACT == 2) v = 1.f / (1.f + expf(-v));
        if (OUT == 0) {
          if (colb < N) Oh[(size_t)(bm + lrow) * ldo + colb] = f2bf(v);
        } else if (OUT == 1) {
          if (colb < N) Of[(size_t)(bm + lrow) * ldo + colb] = v;
        } else {
          if (colb < 256) {
            atomicAdd(&pooled[(size_t)sS[lrow] * 256 + colb], v);
          } else if (colb < 512) {
            Oh[(size_t)(bm + lrow) * 256 + (colb - 256)] = f2bf(v);
          } else {
            atomicAdd(&pooled[(size_t)sO[lrow] * 256 + (colb - 512)], v);
          }
        }
      }
    }
}

template<int ACT, int OUT, bool GATHER>
__global__ __launch_bounds__(256) void mgemm(
    const unsigned short* __restrict__ Ah, int lda,
    const unsigned short* __restrict__ Eh,
    const int* __restrict__ ei,
    const unsigned short* __restrict__ Wh, const unsigned short* __restrict__ Wl,
    const float* __restrict__ bias,
    unsigned short* __restrict__ Oh, int ldo,
    float* __restrict__ Of, float* __restrict__ pooled,
    int M, int N, int K)
{
  mgemm_body<ACT, OUT, GATHER>(Ah, lda, Eh, ei, Wh, Wl, bias, Oh, ldo, Of, pooled,
                               M, N, K, blockIdx.x, blockIdx.y);
}

// ---------------- fused head layers (rel-chain || obj-chain) ----------------------
__global__ __launch_bounds__(256) void head12_fused(
    const unsigned short* __restrict__ rA, int rlda,
    const unsigned short* __restrict__ rWh, const unsigned short* __restrict__ rWl,
    const float* __restrict__ rbias, unsigned short* __restrict__ rO, int rldo,
    int rM, int rN, int rK, int rGX, int rGY,
    const unsigned short* __restrict__ oA, int olda,
    const unsigned short* __restrict__ oWh, const unsigned short* __restrict__ oWl,
    const float* __restrict__ obias, unsigned short* __restrict__ oO, int oldo,
    int oM, int oN, int oK, int oGX)
{
  int b = blockIdx.x;
  const int nrel = rGX * rGY;
  const bool isRel = b < nrel;
  if (!isRel) b -= nrel;
  mgemm_body<1, 0, false>(
      isRel ? rA : oA, isRel ? rlda : olda, nullptr, nullptr,
      isRel ? rWh : oWh, isRel ? rWl : oWl, isRel ? rbias : obias,
      isRel ? rO : oO, isRel ? rldo : oldo, nullptr, nullptr,
      isRel ? rM : oM, isRel ? rN : oN, isRel ? rK : oK,
      b % (isRel ? rGX : oGX), b / (isRel ? rGX : oGX));
}

__global__ __launch_bounds__(256) void head3_fused(
    const unsigned short* __restrict__ rA,
    const unsigned short* __restrict__ rWh, const unsigned short* __restrict__ rWl,
    const float* __restrict__ rbias, float* __restrict__ rOf,
    const unsigned short* __restrict__ oA,
    const unsigned short* __restrict__ oWh, const unsigned short* __restrict__ oWl,
    const float* __restrict__ obias, float* __restrict__ oOf)
{
  int b = blockIdx.x;
  if (b < 64)   // rel: grid (1,64), sigmoid, N=26
    mgemm_body<2, 1, false>(rA, 256, nullptr, nullptr, rWh, rWl, rbias,
                            nullptr, N_REL_CLS, rOf, nullptr, N_EDGES, N_REL_CLS, 256, 0, b);
  else {        // obj: grid (3,8), none, N=160
    b -= 64;
    mgemm_body<0, 1, false>(oA, 256, nullptr, nullptr, oWh, oWl, obias,
                            nullptr, N_OBJ_CLS, oOf, nullptr, N_NODES, N_OBJ_CLS, 256, b % 3, b / 3);
  }
}

// ---------------- helpers ----------------
__global__ __launch_bounds__(256) void count_kernel(const int* __restrict__ ei,
                                                    float* __restrict__ cnt)
{
  const int i = blockIdx.x * blockDim.x + threadIdx.x;
  if (i < 2 * N_EDGES) atomicAdd(&cnt[ei[i]], 1.0f);
}

__global__ __launch_bounds__(256) void avg_plane_kernel(const float* __restrict__ pooled,
                                                        const float* __restrict__ cnt,
                                                        unsigned short* __restrict__ ah)
{
  const int i = blockIdx.x * 256 + threadIdx.x;
  ah[i] = f2bf(pooled[i] / fmaxf(cnt[i >> 8], 1.0f));
}

__global__ __launch_bounds__(256) void logsoftmax_kernel(const float* __restrict__ logits,
                                                         float* __restrict__ out)
{
  __shared__ float red[256];
  const int r = blockIdx.x, tid = threadIdx.x;
  const float v = (tid < N_OBJ_CLS) ? logits[(size_t)r * N_OBJ_CLS + tid] : -INFINITY;
  red[tid] = v;
  __syncthreads();
  for (int s = 128; s > 0; s >>= 1) {
    if (tid < s) red[tid] = fmaxf(red[tid], red[tid + s]);
    __syncthreads();
  }
  const float mxv = red[0];
  __syncthreads();
  red[tid] = (tid < N_OBJ_CLS) ? expf(v - mxv) : 0.0f;
  __syncthreads();
  for (int s = 128; s > 0; s >>= 1) {
    if (tid < s) red[tid] += red[tid + s];
    __syncthreads();
  }
  const float lse = mxv + logf(red[0]);
  if (tid < N_OBJ_CLS) out[(size_t)r * N_OBJ_CLS + tid] = v - lse;
}

// ---------------- launch ----------------
extern "C" void kernel_launch(void* const* d_in, const int* in_sizes, int n_in,
                              void* d_out, int out_size, void* d_ws, size_t ws_size,
                              hipStream_t stream)
{
  const float* obj_points = (const float*)d_in[0];
  const float* rel_points = (const float*)d_in[1];
  const int*   edge_index = (const int*)d_in[2];
  const float* obj_w1 = (const float*)d_in[3];
  const float* obj_b1 = (const float*)d_in[4];
  const float* obj_w2 = (const float*)d_in[5];
  const float* obj_b2 = (const float*)d_in[6];
  const float* obj_w3 = (const float*)d_in[7];
  const float* obj_b3 = (const float*)d_in[8];
  const float* rel_w1 = (const float*)d_in[9];
  const float* rel_b1 = (const float*)d_in[10];
  const float* rel_w2 = (const float*)d_in[11];
  const float* rel_b2 = (const float*)d_in[12];
  const float* rel_w3 = (const float*)d_in[13];
  const float* rel_b3 = (const float*)d_in[14];
  const float* g_tw1 = (const float*)d_in[15];
  const float* g_tb1 = (const float*)d_in[16];
  const float* g_tw2 = (const float*)d_in[17];
  const float* g_tb2 = (const float*)d_in[18];
  const float* g_nw1 = (const float*)d_in[19];
  const float* g_nb1 = (const float*)d_in[20];
  const float* g_nw2 = (const float*)d_in[21];
  const float* g_nb2 = (const float*)d_in[22];
  const float* oc_w1 = (const float*)d_in[23];
  const float* oc_b1 = (const float*)d_in[24];
  const float* oc_w2 = (const float*)d_in[25];
  const float* oc_b2 = (const float*)d_in[26];
  const float* oc_w3 = (const float*)d_in[27];
  const float* oc_b3 = (const float*)d_in[28];
  const float* rc_w1 = (const float*)d_in[29];
  const float* rc_b1 = (const float*)d_in[30];
  const float* rc_w2 = (const float*)d_in[31];
  const float* rc_b2 = (const float*)d_in[32];
  const float* rc_w3 = (const float*)d_in[33];
  const float* rc_b3 = (const float*)d_in[34];
  float* out = (float*)d_out;

  // ---- workspace layout (activations hi-only; weights hi+lo) ----
  unsigned short* u = (unsigned short*)d_ws;
  size_t uo = 0;
  auto UA = [&](size_t n) { unsigned short* p = u + uo; uo += n; return p; };
  unsigned short* x0h = UA(131072);
  unsigned short* x1h = UA(131072);
  unsigned short* e0h = UA(1048576);
  unsigned short* neh = UA(1048576);
  unsigned short* h1h = UA(2097152);
  unsigned short* avgh = UA(131072);
  unsigned short* nhh = UA(262144);
  unsigned short* oh1 = UA(262144);   // obj head scratch 512x512
  unsigned short* oh2 = UA(131072);   // obj head scratch 512x256
  unsigned short* ow2h = UA(8192);   unsigned short* ow2l = UA(8192);
  unsigned short* ow3h = UA(32768);  unsigned short* ow3l = UA(32768);
  unsigned short* rw2h = UA(8192);   unsigned short* rw2l = UA(8192);
  unsigned short* rw3h = UA(32768);  unsigned short* rw3l = UA(32768);
  unsigned short* tw1h[2], *tw1l[2], *tw2h[2], *tw2l[2], *nw1h[2], *nw1l[2], *nw2h[2], *nw2l[2];
  for (int i = 0; i < 2; ++i) { tw1h[i] = UA(393216); tw1l[i] = UA(393216); }
  for (int i = 0; i < 2; ++i) { tw2h[i] = UA(393216); tw2l[i] = UA(393216); }
  for (int i = 0; i < 2; ++i) { nw1h[i] = UA(131072); nw1l[i] = UA(131072); }
  for (int i = 0; i < 2; ++i) { nw2h[i] = UA(131072); nw2l[i] = UA(131072); }
  unsigned short* oc1h = UA(131072); unsigned short* oc1l = UA(131072);
  unsigned short* oc2h = UA(131072); unsigned short* oc2l = UA(131072);
  unsigned short* oc3h = UA(40960);  unsigned short* oc3l = UA(40960);
  unsigned short* rc1h = UA(131072); unsigned short* rc1l = UA(131072);
  unsigned short* rc2h = UA(131072); unsigned short* rc2l = UA(131072);
  unsigned short* rc3h = UA(6656);   unsigned short* rc3l = UA(6656);
  float* f = (float*)(u + ((uo + 7) & ~(size_t)7));
  float* pooled = f;            // 512*256
  float* cntf   = f + 131072;   // 512
  float* logits = f + 131584;   // 512*160
  float* pmax   = f + 213504;   // 4*512*256 obj partial max
  unsigned short* hh1h = h1h;   // rel head scratch aliases dead GNN buffers
  unsigned short* hh2h = e0h;

  // ---- batched weight transpose/split ----
  WBatch wb;
  int cum = 0, wi = 0;
  auto ADD = [&](const float* src, unsigned short* dh, unsigned short* dl, int K, int N) {
    wb.e[wi].src = src; wb.e[wi].dh = dh; wb.e[wi].dl = dl;
    wb.e[wi].K = K; wb.e[wi].N = N; wb.e[wi].start = cum;
    cum += K * N; ++wi;
  };
  ADD(obj_w2, ow2h, ow2l, 64, 128);
  ADD(obj_w3, ow3h, ow3l, 128, 256);
  ADD(rel_w2, rw2h, rw2l, 64, 128);
  ADD(rel_w3, rw3h, rw3l, 128, 256);
  for (int i = 0; i < 2; ++i) ADD(g_tw1 + (size_t)i * 393216, tw1h[i], tw1l[i], 768, 512);
  for (int i = 0; i < 2; ++i) ADD(g_tw2 + (size_t)i * 393216, tw2h[i], tw2l[i], 512, 768);
  for (int i = 0; i < 2; ++i) ADD(g_nw1 + (size_t)i * 131072, nw1h[i], nw1l[i], 256, 512);
  for (int i = 0; i < 2; ++i) ADD(g_nw2 + (size_t)i * 131072, nw2h[i], nw2l[i], 512, 256);
  ADD(oc_w1, oc1h, oc1l, 256, 512);
  ADD(oc_w2, oc2h, oc2l, 512, 256);
  ADD(oc_w3, oc3h, oc3l, 256, 160);
  ADD(rc_w1, rc1h, rc1l, 256, 512);
  ADD(rc_w2, rc2h, rc2l, 512, 256);
  ADD(rc_w3, rc3h, rc3l, 256, 26);
  wb.total = cum;
  hipMemsetAsync(cntf, 0, 512 * sizeof(float), stream);
  wtrans_batch<<<4096, 256, 0, stream>>>(wb);

  // ---- PointNets (128-pt tiles, 8 waves) ----
  pointnet_mfma<3, 512, 4><<<N_NODES * 4, 512, 0, stream>>>(
      obj_points, obj_w1, obj_b1, ow2h, obj_b2, ow3h, obj_b3, nullptr, pmax);
  combine_max<4><<<N_NODES, 256, 0, stream>>>(pmax, obj_b3, x0h);
  pointnet_mfma<4, 256, 1><<<N_EDGES, 512, 0, stream>>>(
      rel_points, rel_w1, rel_b1, rw2h, rel_b2, rw3h, rel_b3, e0h, nullptr);

  // ---- degree counts ----
  count_kernel<<<32, 256, 0, stream>>>(edge_index, cntf);

  // ---- GNN layers (round-11 proven mgemm) ----
  unsigned short *xch = x0h, *xnh = x1h;
  unsigned short *ech = e0h;
  for (int ll = 0; ll < 2; ++ll) {
    mgemm<1, 0, true><<<dim3(8, 64), 256, 0, stream>>>(
        xch, 256, ech, edge_index, tw1h[ll], tw1l[ll], g_tb1 + ll * H_GNN,
        h1h, 512, nullptr, nullptr, N_EDGES, H_GNN, D3);
    hipMemsetAsync(pooled, 0, (size_t)N_NODES * D_NODE * sizeof(float), stream);
    mgemm<0, 2, false><<<dim3(12, 64), 256, 0, stream>>>(
        h1h, 512, nullptr, edge_index, tw2h[ll], tw2l[ll], g_tb2 + ll * D3,
        neh, 256, nullptr, pooled, N_EDGES, D3, H_GNN);
    avg_plane_kernel<<<512, 256, 0, stream>>>(pooled, cntf, avgh);
    mgemm<1, 0, false><<<dim3(8, 8), 256, 0, stream>>>(
        avgh, 256, nullptr, nullptr, nw1h[ll], nw1l[ll], g_nb1 + ll * H_GNN,
        nhh, 512, nullptr, nullptr, N_NODES, H_GNN, D_NODE);
    mgemm<0, 0, false><<<dim3(4, 8), 256, 0, stream>>>(
        nhh, 512, nullptr, nullptr, nw2h[ll], nw2l[ll], g_nb2 + ll * D_NODE,
        xnh, 256, nullptr, nullptr, N_NODES, D_NODE, H_GNN);
    unsigned short* t = xch; xch = xnh; xnh = t;
    ech = neh;
  }

  // ---- heads: rel-chain || obj-chain, fused per layer ----
  head12_fused<<<512 + 64, 256, 0, stream>>>(
      ech, 256, rc1h, rc1l, rc_b1, hh1h, 512, N_EDGES, 512, 256, 8, 64,
      xch, 256, oc1h, oc1l, oc_b1, oh1, 512, N_NODES, 512, 256, 8);
  head12_fused<<<256 + 32, 256, 0, stream>>>(
      hh1h, 512, rc2h, rc2l, rc_b2, hh2h, 256, N_EDGES, 256, 512, 4, 64,
      oh1, 512, oc2h, oc2l, oc_b2, oh2, 256, N_NODES, 256, 512, 4);
  head3_fused<<<64 + 24, 256, 0, stream>>>(
      hh2h, rc3h, rc3l, rc_b3, out + (size_t)N_NODES * N_OBJ_CLS,
      oh2, oc3h, oc3l, oc_b3, logits);
  logsoftmax_kernel<<<N_NODES, 256, 0, stream>>>(logits, out);
}

// Round 18
// 278.231 us; speedup vs baseline: 1.1950x; 1.0113x over previous
//
#include <hip/hip_runtime.h>
#include <hip/hip_bf16.h>
#include <math.h>

#define N_NODES 512
#define N_EDGES 4096
#define D_NODE 256
#define D3 768
#define H_GNN 512
#define N_OBJ_CLS 160
#define N_REL_CLS 26

typedef __attribute__((ext_vector_type(8))) short bf16x8;   // 8 bf16 in 4 VGPRs
typedef __attribute__((ext_vector_type(4))) float f32x4;    // MFMA accumulator

__device__ __forceinline__ unsigned short f2bf(float x) {   // RNE f32 -> bf16 bits
  unsigned u = __float_as_uint(x);
  u = u + 0x7FFFu + ((u >> 16) & 1u);
  return (unsigned short)(u >> 16);
}
__device__ __forceinline__ float bf2f(unsigned short h) {
  return __uint_as_float(((unsigned)h) << 16);
}
// packed RNE cvt: a -> low16, b -> high16 (v_cvt_pk_bf16_f32)
__device__ __forceinline__ unsigned cvtpk(float a, float b) {
  __hip_bfloat162 h = __float22bfloat162_rn(make_float2(a, b));
  return *reinterpret_cast<unsigned*>(&h);
}

// ---------------- batched weight transpose+split: wt[n*K+k] = hi/lo(w[k*N+n]) ----
struct WEnt { const float* src; unsigned short* dh; unsigned short* dl; int K; int N; int start; };
struct WBatch { WEnt e[18]; int total; };

__global__ __launch_bounds__(256) void wtrans_batch(WBatch wb) {
  int idx = blockIdx.x * 256 + threadIdx.x;
  const int stride = gridDim.x * 256;
  for (; idx < wb.total; idx += stride) {
    int i = 0;
#pragma unroll
    for (int t = 1; t < 18; ++t) if (idx >= wb.e[t].start) i = t;
    const int local = idx - wb.e[i].start;
    const int K = wb.e[i].K;
    const int n = local / K, k = local - n * K;
    const float v = wb.e[i].src[k * wb.e[i].N + n];
    const unsigned short hi = f2bf(v);
    wb.e[i].dh[local] = hi;
    wb.e[i].dl[local] = f2bf(v - bf2f(hi));
  }
}

// ---------------- MFMA PointNet: 128-pt tiles, 8 waves, hi-only activations -------
template<int CIN, int PTOT, int NSPLIT>
__global__ __launch_bounds__(512) void pointnet_mfma(
    const float* __restrict__ in,
    const float* __restrict__ w1, const float* __restrict__ b1,
    const unsigned short* __restrict__ w2t, const float* __restrict__ b2,
    const unsigned short* __restrict__ w3t, const float* __restrict__ b3,
    unsigned short* __restrict__ outh,
    float* __restrict__ pmax)
{
  constexpr int PBLK = PTOT / NSPLIT;
  __shared__ unsigned short h1h[128][72];    // [pt][ch] 128x64
  __shared__ unsigned short h2h[128][136];   // [pt][ch] 128x128
  const int tid = threadIdx.x;
  const int wv = tid >> 6, l = tid & 63, lr = l & 15, lg = l >> 4;
  const int blk = blockIdx.x;
  const int b  = blk / NSPLIT;
  const int sp = blk % NSPLIT;
  const float* inb = in + (size_t)b * CIN * PTOT + (size_t)sp * PBLK;

  const int chA = 2 * (l & 31);
  const int sub = l >> 5;
  float w1c0[CIN], w1c1[CIN];
#pragma unroll
  for (int c = 0; c < CIN; ++c) {
    w1c0[c] = w1[c * 64 + chA];
    w1c1[c] = w1[c * 64 + chA + 1];
  }
  const float b1v0 = b1[chA], b1v1 = b1[chA + 1];

  bf16x8 w2f[2];
#pragma unroll
  for (int kt = 0; kt < 2; ++kt)
    w2f[kt] = *(const bf16x8*)(w2t + (size_t)(16 * wv + lr) * 64 + kt * 32 + lg * 8);
  bf16x8 w3f[2][4];
#pragma unroll
  for (int mt = 0; mt < 2; ++mt)
#pragma unroll
    for (int kt = 0; kt < 4; ++kt)
      w3f[mt][kt] = *(const bf16x8*)(w3t + (size_t)(32 * wv + mt * 16 + lr) * 128 + kt * 32 + lg * 8);

  const float4 b2v = *(const float4*)&b2[16 * wv + lg * 4];

  f32x4 mxf[2];
#pragma unroll
  for (int mt = 0; mt < 2; ++mt) { f32x4 z = {-INFINITY, -INFINITY, -INFINITY, -INFINITY}; mxf[mt] = z; }

  for (int t0 = 0; t0 < PBLK; t0 += 128) {
    // ---- A: L1 f32; vectorized float4 input loads (2 ch x 8 pts per lane) ----
    {
      const int pl0 = wv * 16 + sub * 8;
      float4 xv0[CIN], xv1[CIN];
#pragma unroll
      for (int c = 0; c < CIN; ++c) {
        xv0[c] = *(const float4*)&inb[c * PTOT + t0 + pl0];
        xv1[c] = *(const float4*)&inb[c * PTOT + t0 + pl0 + 4];
      }
#pragma unroll
      for (int pp = 0; pp < 8; ++pp) {
        float a0 = b1v0, a1 = b1v1;
#pragma unroll
        for (int c = 0; c < CIN; ++c) {
          const float xc = (pp < 4) ? ((const float*)&xv0[c])[pp]
                                    : ((const float*)&xv1[c])[pp - 4];
          a0 = fmaf(xc, w1c0[c], a0);
          a1 = fmaf(xc, w1c1[c], a1);
        }
        a0 = fmaxf(a0, 0.f); a1 = fmaxf(a1, 0.f);
        *(unsigned*)&h1h[pl0 + pp][chA] = cvtpk(a0, a1);
      }
    }
    __syncthreads();
    // ---- B: L2; wave owns ch [16wv,+16), all 128 pts ----
#pragma unroll
    for (int ntt = 0; ntt < 8; ++ntt) {
      bf16x8 bh[2];
#pragma unroll
      for (int kt = 0; kt < 2; ++kt)
        bh[kt] = *(const bf16x8*)&h1h[ntt * 16 + lr][kt * 32 + lg * 8];
      f32x4 a = {0.f, 0.f, 0.f, 0.f};
#pragma unroll
      for (int kt = 0; kt < 2; ++kt)
        a = __builtin_amdgcn_mfma_f32_16x16x32_bf16(w2f[kt], bh[kt], a, 0, 0, 0);
      const float v0 = fmaxf(a[0] + b2v.x, 0.f);
      const float v1 = fmaxf(a[1] + b2v.y, 0.f);
      const float v2 = fmaxf(a[2] + b2v.z, 0.f);
      const float v3 = fmaxf(a[3] + b2v.w, 0.f);
      const int pr = ntt * 16 + lr, cc = 16 * wv + lg * 4;
      *(uint2*)&h2h[pr][cc] = make_uint2(cvtpk(v0, v1), cvtpk(v2, v3));
    }
    __syncthreads();
    // ---- C: L3 + running max; wave owns ch [32wv,+32), all 128 pts ----
#pragma unroll
    for (int ntt = 0; ntt < 8; ++ntt) {
      bf16x8 ah[4];
#pragma unroll
      for (int kt = 0; kt < 4; ++kt)
        ah[kt] = *(const bf16x8*)&h2h[ntt * 16 + lr][kt * 32 + lg * 8];
#pragma unroll
      for (int mt = 0; mt < 2; ++mt) {
        f32x4 a = {0.f, 0.f, 0.f, 0.f};
#pragma unroll
        for (int kt = 0; kt < 4; ++kt)
          a = __builtin_amdgcn_mfma_f32_16x16x32_bf16(w3f[mt][kt], ah[kt], a, 0, 0, 0);
#pragma unroll
        for (int j = 0; j < 4; ++j) mxf[mt][j] = fmaxf(mxf[mt][j], a[j]);
      }
    }
    __syncthreads();
  }
  // reduce over the 16-lane point axis
#pragma unroll
  for (int mt = 0; mt < 2; ++mt)
#pragma unroll
    for (int j = 0; j < 4; ++j) {
      float v = mxf[mt][j];
      v = fmaxf(v, __shfl_xor(v, 1));
      v = fmaxf(v, __shfl_xor(v, 2));
      v = fmaxf(v, __shfl_xor(v, 4));
      v = fmaxf(v, __shfl_xor(v, 8));
      mxf[mt][j] = v;
    }
  if (lr == 0) {
    if (NSPLIT == 1) {
#pragma unroll
      for (int mt = 0; mt < 2; ++mt) {
        const int ch = 32 * wv + mt * 16 + lg * 4;
        const float4 b3v = *(const float4*)&b3[ch];
        const size_t o = (size_t)b * 256 + ch;
        *(uint2*)(outh + o) = make_uint2(cvtpk(mxf[mt][0] + b3v.x, mxf[mt][1] + b3v.y),
                                         cvtpk(mxf[mt][2] + b3v.z, mxf[mt][3] + b3v.w));
      }
    } else {
#pragma unroll
      for (int mt = 0; mt < 2; ++mt) {
        const int ch = 32 * wv + mt * 16 + lg * 4;
        const size_t o = ((size_t)b * NSPLIT + sp) * 256 + ch;
        *(float4*)&pmax[o] = make_float4(mxf[mt][0], mxf[mt][1], mxf[mt][2], mxf[mt][3]);
      }
    }
  }
}

template<int NSPLIT>
__global__ __launch_bounds__(256) void combine_max(
    const float* __restrict__ pmax, const float* __restrict__ b3,
    unsigned short* __restrict__ outh)
{
  const int b = blockIdx.x, ch = threadIdx.x;
  float m = pmax[(size_t)b * NSPLIT * 256 + ch];
#pragma unroll
  for (int s = 1; s < NSPLIT; ++s)
    m = fmaxf(m, pmax[((size_t)b * NSPLIT + s) * 256 + ch]);
  outh[(size_t)b * 256 + ch] = f2bf(m + b3[ch]);
}

// ---------------- MFMA GEMM body, BK=128 + T14 register prefetch ------------------
// Same k-order as BK=64 version (kt ascending, steps ascending) -> bit-identical.
// Half the barrier pairs; 12x16B prefetch registers (fine at 2 blocks/CU).
template<int ACT, int OUT, bool GATHER>
__device__ __forceinline__ void mgemm_body(
    const unsigned short* __restrict__ Ah, int lda,
    const unsigned short* __restrict__ Eh,
    const int* __restrict__ ei,
    const unsigned short* __restrict__ Wh, const unsigned short* __restrict__ Wl,
    const float* __restrict__ bias,
    unsigned short* __restrict__ Oh, int ldo,
    float* __restrict__ Of, float* __restrict__ pooled,
    int M, int N, int K, int bx, int by)
{
  __shared__ unsigned short sAh[64][136];
  __shared__ unsigned short sBh[64][136], sBl[64][136];
  __shared__ int sS[64], sO[64];
  const int tid = threadIdx.x;
  const int wv = tid >> 6, l = tid & 63, lr = l & 15, lg = l >> 4;
  const int wm = wv >> 1, wn = wv & 1;
  const int bm = by * 64, bn = bx * 64;
  const int srow = tid >> 4;        // 0..15
  const int sch  = (tid & 15) * 8;  // 0..120

  if ((GATHER || OUT == 2) && tid < 64) {
    sS[tid] = ei[bm + tid];
    sO[tid] = ei[N_EDGES + bm + tid];
  }
  __syncthreads();

  float bv[2];
#pragma unroll
  for (int ni = 0; ni < 2; ++ni) {
    const int col = bn + wn * 32 + ni * 16 + lr;
    bv[ni] = (col < N) ? bias[col] : 0.f;
  }

  f32x4 acc[2][2];
#pragma unroll
  for (int mi = 0; mi < 2; ++mi)
#pragma unroll
    for (int ni = 0; ni < 2; ++ni) { f32x4 z = {0.f, 0.f, 0.f, 0.f}; acc[mi][ni] = z; }

  const int nsteps = K >> 7;

  auto loadA = [&](int k0, int it) -> bf16x8 {
    const int r = it * 16 + srow;
    const unsigned short* ph;
    if (GATHER) {
      const int kg = k0 + sch;   // 128-chunks align with 256-segments
      if (kg < 256)      ph = Ah + (size_t)sS[r] * 256 + kg;
      else if (kg < 512) ph = Eh + (size_t)(bm + r) * 256 + (kg - 256);
      else               ph = Ah + (size_t)sO[r] * 256 + (kg - 512);
    } else {
      ph = Ah + (size_t)(bm + r) * lda + k0 + sch;
    }
    return *(const bf16x8*)ph;
  };
  auto loadB = [&](const unsigned short* W, int k0, int it) -> bf16x8 {
    int n = bn + it * 16 + srow;
    if (n >= N) n = N - 1;
    return *(const bf16x8*)(W + (size_t)n * K + k0 + sch);
  };

  bf16x8 rA[4], rBh[4], rBl[4];
#pragma unroll
  for (int it = 0; it < 4; ++it) {
    rA[it]  = loadA(0, it);
    rBh[it] = loadB(Wh, 0, it);
    rBl[it] = loadB(Wl, 0, it);
  }

  for (int t = 0; t < nsteps; ++t) {
    __syncthreads();
#pragma unroll
    for (int it = 0; it < 4; ++it) {
      const int r = it * 16 + srow;
      *(bf16x8*)&sAh[r][sch] = rA[it];
      *(bf16x8*)&sBh[r][sch] = rBh[it];
      *(bf16x8*)&sBl[r][sch] = rBl[it];
    }
    __syncthreads();
    if (t + 1 < nsteps) {
      const int k1 = (t + 1) << 7;
#pragma unroll
      for (int it = 0; it < 4; ++it) {
        rA[it]  = loadA(k1, it);
        rBh[it] = loadB(Wh, k1, it);
        rBl[it] = loadB(Wl, k1, it);
      }
    }
#pragma unroll
    for (int kt = 0; kt < 4; ++kt) {
      bf16x8 afh[2], bfh[2], bfl[2];
#pragma unroll
      for (int mi = 0; mi < 2; ++mi)
        afh[mi] = *(const bf16x8*)&sAh[wm * 32 + mi * 16 + lr][kt * 32 + lg * 8];
#pragma unroll
      for (int ni = 0; ni < 2; ++ni) {
        bfh[ni] = *(const bf16x8*)&sBh[wn * 32 + ni * 16 + lr][kt * 32 + lg * 8];
        bfl[ni] = *(const bf16x8*)&sBl[wn * 32 + ni * 16 + lr][kt * 32 + lg * 8];
      }
#pragma unroll
      for (int mi = 0; mi < 2; ++mi)
#pragma unroll
        for (int ni = 0; ni < 2; ++ni) {
          acc[mi][ni] = __builtin_amdgcn_mfma_f32_16x16x32_bf16(afh[mi], bfh[ni], acc[mi][ni], 0, 0, 0);
          acc[mi][ni] = __builtin_amdgcn_mfma_f32_16x16x32_bf16(afh[mi], bfl[ni], acc[mi][ni], 0, 0, 0);
        }
    }
  }
#pragma unroll
  for (int mi = 0; mi < 2; ++mi)
#pragma unroll
    for (int ni = 0; ni < 2; ++ni) {
      const int colb = bn + wn * 32 + ni * 16 + lr;
#pragma unroll
      for (int j = 0; j < 4; ++j) {
        const int lrow = wm * 32 + mi * 16 + lg * 4 + j;
        float v = acc[mi][ni][j] + bv[ni];
        if (ACT == 1) v = fmaxf(v, 0.f);
        else if (ACT == 2) v = 1.f / (1.f + expf(-v));
        if (OUT == 0) {
          if (colb < N) Oh[(size_t)(bm + lrow) * ldo + colb] = f2bf(v);
        } else if (OUT == 1) {
          if (colb < N) Of[(size_t)(bm + lrow) * ldo + colb] = v;
        } else {
          if (colb < 256) {
            atomicAdd(&pooled[(size_t)sS[lrow] * 256 + colb], v);
          } else if (colb < 512) {
            Oh[(size_t)(bm + lrow) * 256 + (colb - 256)] = f2bf(v);
          } else {
            atomicAdd(&pooled[(size_t)sO[lrow] * 256 + (colb - 512)], v);
          }
        }
      }
    }
}

template<int ACT, int OUT, bool GATHER>
__global__ __launch_bounds__(256) void mgemm(
    const unsigned short* __restrict__ Ah, int lda,
    const unsigned short* __restrict__ Eh,
    const int* __restrict__ ei,
    const unsigned short* __restrict__ Wh, const unsigned short* __restrict__ Wl,
    const float* __restrict__ bias,
    unsigned short* __restrict__ Oh, int ldo,
    float* __restrict__ Of, float* __restrict__ pooled,
    int M, int N, int K)
{
  mgemm_body<ACT, OUT, GATHER>(Ah, lda, Eh, ei, Wh, Wl, bias, Oh, ldo, Of, pooled,
                               M, N, K, blockIdx.x, blockIdx.y);
}

// ---------------- fused head layers (rel-chain || obj-chain) ----------------------
__global__ __launch_bounds__(256) void head12_fused(
    const unsigned short* __restrict__ rA, int rlda,
    const unsigned short* __restrict__ rWh, const unsigned short* __restrict__ rWl,
    const float* __restrict__ rbias, unsigned short* __restrict__ rO, int rldo,
    int rM, int rN, int rK, int rGX, int rGY,
    const unsigned short* __restrict__ oA, int olda,
    const unsigned short* __restrict__ oWh, const unsigned short* __restrict__ oWl,
    const float* __restrict__ obias, unsigned short* __restrict__ oO, int oldo,
    int oM, int oN, int oK, int oGX)
{
  int b = blockIdx.x;
  const int nrel = rGX * rGY;
  const bool isRel = b < nrel;
  if (!isRel) b -= nrel;
  mgemm_body<1, 0, false>(
      isRel ? rA : oA, isRel ? rlda : olda, nullptr, nullptr,
      isRel ? rWh : oWh, isRel ? rWl : oWl, isRel ? rbias : obias,
      isRel ? rO : oO, isRel ? rldo : oldo, nullptr, nullptr,
      isRel ? rM : oM, isRel ? rN : oN, isRel ? rK : oK,
      b % (isRel ? rGX : oGX), b / (isRel ? rGX : oGX));
}

__global__ __launch_bounds__(256) void head3_fused(
    const unsigned short* __restrict__ rA,
    const unsigned short* __restrict__ rWh, const unsigned short* __restrict__ rWl,
    const float* __restrict__ rbias, float* __restrict__ rOf,
    const unsigned short* __restrict__ oA,
    const unsigned short* __restrict__ oWh, const unsigned short* __restrict__ oWl,
    const float* __restrict__ obias, float* __restrict__ oOf)
{
  int b = blockIdx.x;
  if (b < 64)   // rel: grid (1,64), sigmoid, N=26
    mgemm_body<2, 1, false>(rA, 256, nullptr, nullptr, rWh, rWl, rbias,
                            nullptr, N_REL_CLS, rOf, nullptr, N_EDGES, N_REL_CLS, 256, 0, b);
  else {        // obj: grid (3,8), none, N=160
    b -= 64;
    mgemm_body<0, 1, false>(oA, 256, nullptr, nullptr, oWh, oWl, obias,
                            nullptr, N_OBJ_CLS, oOf, nullptr, N_NODES, N_OBJ_CLS, 256, b % 3, b / 3);
  }
}

// ---------------- helpers ----------------
__global__ __launch_bounds__(256) void count_kernel(const int* __restrict__ ei,
                                                    float* __restrict__ cnt)
{
  const int i = blockIdx.x * blockDim.x + threadIdx.x;
  if (i < 2 * N_EDGES) atomicAdd(&cnt[ei[i]], 1.0f);
}

__global__ __launch_bounds__(256) void avg_plane_kernel(const float* __restrict__ pooled,
                                                        const float* __restrict__ cnt,
                                                        unsigned short* __restrict__ ah)
{
  const int i = blockIdx.x * 256 + threadIdx.x;
  ah[i] = f2bf(pooled[i] / fmaxf(cnt[i >> 8], 1.0f));
}

__global__ __launch_bounds__(256) void logsoftmax_kernel(const float* __restrict__ logits,
                                                         float* __restrict__ out)
{
  __shared__ float red[256];
  const int r = blockIdx.x, tid = threadIdx.x;
  const float v = (tid < N_OBJ_CLS) ? logits[(size_t)r * N_OBJ_CLS + tid] : -INFINITY;
  red[tid] = v;
  __syncthreads();
  for (int s = 128; s > 0; s >>= 1) {
    if (tid < s) red[tid] = fmaxf(red[tid], red[tid + s]);
    __syncthreads();
  }
  const float mxv = red[0];
  __syncthreads();
  red[tid] = (tid < N_OBJ_CLS) ? expf(v - mxv) : 0.0f;
  __syncthreads();
  for (int s = 128; s > 0; s >>= 1) {
    if (tid < s) red[tid] += red[tid + s];
    __syncthreads();
  }
  const float lse = mxv + logf(red[0]);
  if (tid < N_OBJ_CLS) out[(size_t)r * N_OBJ_CLS + tid] = v - lse;
}

// ---------------- launch ----------------
extern "C" void kernel_launch(void* const* d_in, const int* in_sizes, int n_in,
                              void* d_out, int out_size, void* d_ws, size_t ws_size,
                              hipStream_t stream)
{
  const float* obj_points = (const float*)d_in[0];
  const float* rel_points = (const float*)d_in[1];
  const int*   edge_index = (const int*)d_in[2];
  const float* obj_w1 = (const float*)d_in[3];
  const float* obj_b1 = (const float*)d_in[4];
  const float* obj_w2 = (const float*)d_in[5];
  const float* obj_b2 = (const float*)d_in[6];
  const float* obj_w3 = (const float*)d_in[7];
  const float* obj_b3 = (const float*)d_in[8];
  const float* rel_w1 = (const float*)d_in[9];
  const float* rel_b1 = (const float*)d_in[10];
  const float* rel_w2 = (const float*)d_in[11];
  const float* rel_b2 = (const float*)d_in[12];
  const float* rel_w3 = (const float*)d_in[13];
  const float* rel_b3 = (const float*)d_in[14];
  const float* g_tw1 = (const float*)d_in[15];
  const float* g_tb1 = (const float*)d_in[16];
  const float* g_tw2 = (const float*)d_in[17];
  const float* g_tb2 = (const float*)d_in[18];
  const float* g_nw1 = (const float*)d_in[19];
  const float* g_nb1 = (const float*)d_in[20];
  const float* g_nw2 = (const float*)d_in[21];
  const float* g_nb2 = (const float*)d_in[22];
  const float* oc_w1 = (const float*)d_in[23];
  const float* oc_b1 = (const float*)d_in[24];
  const float* oc_w2 = (const float*)d_in[25];
  const float* oc_b2 = (const float*)d_in[26];
  const float* oc_w3 = (const float*)d_in[27];
  const float* oc_b3 = (const float*)d_in[28];
  const float* rc_w1 = (const float*)d_in[29];
  const float* rc_b1 = (const float*)d_in[30];
  const float* rc_w2 = (const float*)d_in[31];
  const float* rc_b2 = (const float*)d_in[32];
  const float* rc_w3 = (const float*)d_in[33];
  const float* rc_b3 = (const float*)d_in[34];
  float* out = (float*)d_out;

  // ---- workspace layout (activations hi-only; weights hi+lo) ----
  unsigned short* u = (unsigned short*)d_ws;
  size_t uo = 0;
  auto UA = [&](size_t n) { unsigned short* p = u + uo; uo += n; return p; };
  unsigned short* x0h = UA(131072);
  unsigned short* x1h = UA(131072);
  unsigned short* e0h = UA(1048576);
  unsigned short* neh = UA(1048576);
  unsigned short* h1h = UA(2097152);
  unsigned short* avgh = UA(131072);
  unsigned short* nhh = UA(262144);
  unsigned short* oh1 = UA(262144);   // obj head scratch 512x512
  unsigned short* oh2 = UA(131072);   // obj head scratch 512x256
  unsigned short* ow2h = UA(8192);   unsigned short* ow2l = UA(8192);
  unsigned short* ow3h = UA(32768);  unsigned short* ow3l = UA(32768);
  unsigned short* rw2h = UA(8192);   unsigned short* rw2l = UA(8192);
  unsigned short* rw3h = UA(32768);  unsigned short* rw3l = UA(32768);
  unsigned short* tw1h[2], *tw1l[2], *tw2h[2], *tw2l[2], *nw1h[2], *nw1l[2], *nw2h[2], *nw2l[2];
  for (int i = 0; i < 2; ++i) { tw1h[i] = UA(393216); tw1l[i] = UA(393216); }
  for (int i = 0; i < 2; ++i) { tw2h[i] = UA(393216); tw2l[i] = UA(393216); }
  for (int i = 0; i < 2; ++i) { nw1h[i] = UA(131072); nw1l[i] = UA(131072); }
  for (int i = 0; i < 2; ++i) { nw2h[i] = UA(131072); nw2l[i] = UA(131072); }
  unsigned short* oc1h = UA(131072); unsigned short* oc1l = UA(131072);
  unsigned short* oc2h = UA(131072); unsigned short* oc2l = UA(131072);
  unsigned short* oc3h = UA(40960);  unsigned short* oc3l = UA(40960);
  unsigned short* rc1h = UA(131072); unsigned short* rc1l = UA(131072);
  unsigned short* rc2h = UA(131072); unsigned short* rc2l = UA(131072);
  unsigned short* rc3h = UA(6656);   unsigned short* rc3l = UA(6656);
  float* f = (float*)(u + ((uo + 7) & ~(size_t)7));
  float* pooled = f;            // 512*256
  float* cntf   = f + 131072;   // 512
  float* logits = f + 131584;   // 512*160
  float* pmax   = f + 213504;   // 4*512*256 obj partial max
  unsigned short* hh1h = h1h;   // rel head scratch aliases dead GNN buffers
  unsigned short* hh2h = e0h;

  // ---- batched weight transpose/split ----
  WBatch wb;
  int cum = 0, wi = 0;
  auto ADD = [&](const float* src, unsigned short* dh, unsigned short* dl, int K, int N) {
    wb.e[wi].src = src; wb.e[wi].dh = dh; wb.e[wi].dl = dl;
    wb.e[wi].K = K; wb.e[wi].N = N; wb.e[wi].start = cum;
    cum += K * N; ++wi;
  };
  ADD(obj_w2, ow2h, ow2l, 64, 128);
  ADD(obj_w3, ow3h, ow3l, 128, 256);
  ADD(rel_w2, rw2h, rw2l, 64, 128);
  ADD(rel_w3, rw3h, rw3l, 128, 256);
  for (int i = 0; i < 2; ++i) ADD(g_tw1 + (size_t)i * 393216, tw1h[i], tw1l[i], 768, 512);
  for (int i = 0; i < 2; ++i) ADD(g_tw2 + (size_t)i * 393216, tw2h[i], tw2l[i], 512, 768);
  for (int i = 0; i < 2; ++i) ADD(g_nw1 + (size_t)i * 131072, nw1h[i], nw1l[i], 256, 512);
  for (int i = 0; i < 2; ++i) ADD(g_nw2 + (size_t)i * 131072, nw2h[i], nw2l[i], 512, 256);
  ADD(oc_w1, oc1h, oc1l, 256, 512);
  ADD(oc_w2, oc2h, oc2l, 512, 256);
  ADD(oc_w3, oc3h, oc3l, 256, 160);
  ADD(rc_w1, rc1h, rc1l, 256, 512);
  ADD(rc_w2, rc2h, rc2l, 512, 256);
  ADD(rc_w3, rc3h, rc3l, 256, 26);
  wb.total = cum;
  hipMemsetAsync(cntf, 0, 512 * sizeof(float), stream);
  wtrans_batch<<<4096, 256, 0, stream>>>(wb);

  // ---- PointNets (128-pt tiles, 8 waves) ----
  pointnet_mfma<3, 512, 4><<<N_NODES * 4, 512, 0, stream>>>(
      obj_points, obj_w1, obj_b1, ow2h, obj_b2, ow3h, obj_b3, nullptr, pmax);
  combine_max<4><<<N_NODES, 256, 0, stream>>>(pmax, obj_b3, x0h);
  pointnet_mfma<4, 256, 1><<<N_EDGES, 512, 0, stream>>>(
      rel_points, rel_w1, rel_b1, rw2h, rel_b2, rw3h, rel_b3, e0h, nullptr);

  // ---- degree counts ----
  count_kernel<<<32, 256, 0, stream>>>(edge_index, cntf);

  // ---- GNN layers (BK=128 mgemm) ----
  unsigned short *xch = x0h, *xnh = x1h;
  unsigned short *ech = e0h;
  for (int ll = 0; ll < 2; ++ll) {
    mgemm<1, 0, true><<<dim3(8, 64), 256, 0, stream>>>(
        xch, 256, ech, edge_index, tw1h[ll], tw1l[ll], g_tb1 + ll * H_GNN,
        h1h, 512, nullptr, nullptr, N_EDGES, H_GNN, D3);
    hipMemsetAsync(pooled, 0, (size_t)N_NODES * D_NODE * sizeof(float), stream);
    mgemm<0, 2, false><<<dim3(12, 64), 256, 0, stream>>>(
        h1h, 512, nullptr, edge_index, tw2h[ll], tw2l[ll], g_tb2 + ll * D3,
        neh, 256, nullptr, pooled, N_EDGES, D3, H_GNN);
    avg_plane_kernel<<<512, 256, 0, stream>>>(pooled, cntf, avgh);
    mgemm<1, 0, false><<<dim3(8, 8), 256, 0, stream>>>(
        avgh, 256, nullptr, nullptr, nw1h[ll], nw1l[ll], g_nb1 + ll * H_GNN,
        nhh, 512, nullptr, nullptr, N_NODES, H_GNN, D_NODE);
    mgemm<0, 0, false><<<dim3(4, 8), 256, 0, stream>>>(
        nhh, 512, nullptr, nullptr, nw2h[ll], nw2l[ll], g_nb2 + ll * D_NODE,
        xnh, 256, nullptr, nullptr, N_NODES, D_NODE, H_GNN);
    unsigned short* t = xch; xch = xnh; xnh = t;
    ech = neh;
  }

  // ---- heads: rel-chain || obj-chain, fused per layer ----
  head12_fused<<<512 + 64, 256, 0, stream>>>(
      ech, 256, rc1h, rc1l, rc_b1, hh1h, 512, N_EDGES, 512, 256, 8, 64,
      xch, 256, oc1h, oc1l, oc_b1, oh1, 512, N_NODES, 512, 256, 8);
  head12_fused<<<256 + 32, 256, 0, stream>>>(
      hh1h, 512, rc2h, rc2l, rc_b2, hh2h, 256, N_EDGES, 256, 512, 4, 64,
      oh1, 512, oc2h, oc2l, oc_b2, oh2, 256, N_NODES, 256, 512, 4);
  head3_fused<<<64 + 24, 256, 0, stream>>>(
      hh2h, rc3h, rc3l, rc_b3, out + (size_t)N_NODES * N_OBJ_CLS,
      oh2, oc3h, oc3l, oc_b3, logits);
  logsoftmax_kernel<<<N_NODES, 256, 0, stream>>>(logits, out);
}